// Round 2
// baseline (2142.737 us; speedup 1.0000x reference)
//
#include <hip/hip_runtime.h>

#define THREADS 256

// v[i] = x[i] for inputs else 0 ; nxt[i] = bias-init for the first step
__global__ void prep_kernel(const float* __restrict__ x,
                            const float* __restrict__ bias,
                            float* __restrict__ v, float* __restrict__ nxt,
                            int N, int IN) {
    int i = blockIdx.x * THREADS + threadIdx.x;
    if (i >= N) return;
    v[i]   = (i < IN) ? x[i] : 0.0f;
    nxt[i] = (i < IN) ? 0.0f : bias[i - IN];
}

// Step-0 edge kernel: v is zero except neurons [0, IN) -> skip ~99.6% of edges.
// Only the src stream is read unconditionally; dst/w loads are predicated.
__global__ void edge0_kernel(const int* __restrict__ src,
                             const int* __restrict__ dst,
                             const float* __restrict__ w,
                             const float* __restrict__ v,
                             float* __restrict__ nxt,
                             int E, int IN) {
    int k = blockIdx.x * THREADS + threadIdx.x;
    int E4 = E >> 2;
    if (k < E4) {
        int4 s = ((const int4*)src)[k];
        int b = k << 2;
        if (s.x < IN) atomicAdd(&nxt[dst[b + 0]], v[s.x] * w[b + 0]);
        if (s.y < IN) atomicAdd(&nxt[dst[b + 1]], v[s.y] * w[b + 1]);
        if (s.z < IN) atomicAdd(&nxt[dst[b + 2]], v[s.z] * w[b + 2]);
        if (s.w < IN) atomicAdd(&nxt[dst[b + 3]], v[s.w] * w[b + 3]);
    }
    if (k == 0) {  // tail (E % 4), at most 3 edges
        for (int e = E4 << 2; e < E; ++e) {
            int s = src[e];
            if (s < IN) atomicAdd(&nxt[dst[e]], v[s] * w[e]);
        }
    }
}

// Generic edge kernel: nxt[dst[e]] += v[src[e]] * w[e]
__global__ void edge_kernel(const int* __restrict__ src,
                            const int* __restrict__ dst,
                            const float* __restrict__ w,
                            const float* __restrict__ v,
                            float* __restrict__ nxt,
                            int E) {
    int k = blockIdx.x * THREADS + threadIdx.x;
    int E4 = E >> 2;
    if (k < E4) {
        int4 s = ((const int4*)src)[k];
        int4 d = ((const int4*)dst)[k];
        float4 wv = ((const float4*)w)[k];
        atomicAdd(&nxt[d.x], v[s.x] * wv.x);
        atomicAdd(&nxt[d.y], v[s.y] * wv.y);
        atomicAdd(&nxt[d.z], v[s.z] * wv.z);
        atomicAdd(&nxt[d.w], v[s.w] * wv.w);
    }
    if (k == 0) {  // tail
        for (int e = E4 << 2; e < E; ++e)
            atomicAdd(&nxt[dst[e]], v[src[e]] * w[e]);
    }
}

// v = isOutput ? nxt : tanh(nxt); re-init nxt with bias for the next step;
// on the last step also emit fp32 outputs.
__global__ void finalize_kernel(float* __restrict__ nxt,
                                float* __restrict__ v,
                                const float* __restrict__ bias,
                                float* __restrict__ out,  // null except last step
                                int N, int IN, int OUT) {
    int i = blockIdx.x * THREADS + threadIdx.x;
    if (i >= N) return;
    float val = nxt[i];
    bool isOut = (i >= N - OUT);
    float a = isOut ? val : tanhf(val);
    v[i] = a;
    nxt[i] = (i < IN) ? 0.0f : bias[i - IN];
    if (out != nullptr && isOut) out[i - (N - OUT)] = a;
}

extern "C" void kernel_launch(void* const* d_in, const int* in_sizes, int n_in,
                              void* d_out, int out_size, void* d_ws, size_t ws_size,
                              hipStream_t stream) {
    // setup_inputs order:
    // 0: x [IN] f32, 1: synapse_weights [E] f32, 2: neuron_biases [N-IN] f32,
    // 3: synapse_src [E] i32, 4: synapse_dst [E] i32,
    // 5: input_indices, 6: output_indices, 7: non_input_indices (aranges, unused)
    const float* x    = (const float*)d_in[0];
    const float* w    = (const float*)d_in[1];
    const float* bias = (const float*)d_in[2];
    const int* src = (const int*)d_in[3];
    const int* dst = (const int*)d_in[4];

    const int IN  = in_sizes[0];
    const int E   = in_sizes[1];
    const int N   = IN + in_sizes[2];
    const int OUT = out_size;

    float* v   = (float*)d_ws;       // N fp32
    float* nxt = v + N;              // N fp32

    int nBlocks = (N + THREADS - 1) / THREADS;
    int eBlocks = ((E >> 2) + THREADS - 1) / THREADS;

    prep_kernel<<<nBlocks, THREADS, 0, stream>>>(x, bias, v, nxt, N, IN);

    const int STEPS = 3;
    for (int step = 0; step < STEPS; ++step) {
        if (step == 0)
            edge0_kernel<<<eBlocks, THREADS, 0, stream>>>(src, dst, w, v, nxt, E, IN);
        else
            edge_kernel<<<eBlocks, THREADS, 0, stream>>>(src, dst, w, v, nxt, E);
        float* outp = (step == STEPS - 1) ? (float*)d_out : nullptr;
        finalize_kernel<<<nBlocks, THREADS, 0, stream>>>(nxt, v, bias, outp, N, IN, OUT);
    }
}

// Round 3
// 1107.280 us; speedup vs baseline: 1.9351x; 1.9351x over previous
//
#include <hip/hip_runtime.h>

#define THREADS 256
#define BSHIFT 10
#define BSIZE 1024            // neurons per bucket (fits LDS fp32 accumulator)
#define SC_CHUNK 32768        // edges per scatter block (256 thr x 128)
typedef unsigned int u32;

// ---------------- fast path: bucketized gather ----------------

// vA[i] = x[i] for inputs else 0
__global__ void prep2_kernel(const float* __restrict__ x, float* __restrict__ vA,
                             int N, int IN) {
    int i = blockIdx.x * THREADS + threadIdx.x;
    if (i < N) vA[i] = (i < IN) ? x[i] : 0.0f;
}

// LDS-privatized histogram of dst into coarse buckets
__global__ void histo_kernel(const int* __restrict__ dst, u32* __restrict__ ghisto,
                             int E) {
    __shared__ u32 h[BSIZE];
    for (int i = threadIdx.x; i < BSIZE; i += THREADS) h[i] = 0;
    __syncthreads();
    int stride = gridDim.x * THREADS;
    for (int e = blockIdx.x * THREADS + threadIdx.x; e < E; e += stride)
        atomicAdd(&h[((u32)dst[e]) >> BSHIFT], 1u);
    __syncthreads();
    for (int i = threadIdx.x; i < BSIZE; i += THREADS) {
        u32 c = h[i];
        if (c) atomicAdd(&ghisto[i], c);
    }
}

// single-block exclusive scan over <=1024 bucket counts
__global__ void scan_kernel(const u32* __restrict__ ghisto, u32* __restrict__ gbase,
                            u32* __restrict__ gcursor, int NB) {
    __shared__ u32 s[1024];
    int t = threadIdx.x;
    u32 own = (t < NB) ? ghisto[t] : 0u;
    s[t] = own;
    __syncthreads();
    for (int off = 1; off < 1024; off <<= 1) {
        u32 v = (t >= off) ? s[t - off] : 0u;
        __syncthreads();
        s[t] += v;
        __syncthreads();
    }
    u32 excl = s[t] - own;
    if (t < NB) { gbase[t] = excl; gcursor[t] = excl; }
    if (t == NB - 1) gbase[NB] = s[t];   // total == E
}

// scatter edges into bucket-grouped records: (src | dst_local<<20, w)
__global__ void scatter_kernel(const int* __restrict__ src, const int* __restrict__ dst,
                               const float* __restrict__ w, u32* __restrict__ gcursor,
                               uint2* __restrict__ e8, int E) {
    __shared__ u32 h[BSIZE];
    int start = blockIdx.x * SC_CHUNK;
    int end = start + SC_CHUNK; if (end > E) end = E;
    for (int i = threadIdx.x; i < BSIZE; i += THREADS) h[i] = 0;
    __syncthreads();
    for (int e = start + threadIdx.x; e < end; e += THREADS)
        atomicAdd(&h[((u32)dst[e]) >> BSHIFT], 1u);
    __syncthreads();
    for (int i = threadIdx.x; i < BSIZE; i += THREADS) {
        u32 c = h[i];
        h[i] = c ? atomicAdd(&gcursor[i], c) : 0u;   // reserve contiguous range
    }
    __syncthreads();
    for (int e = start + threadIdx.x; e < end; e += THREADS) {
        u32 d = (u32)dst[e];
        u32 b0 = d >> BSHIFT;
        u32 pos = atomicAdd(&h[b0], 1u);
        e8[pos] = make_uint2((u32)src[e] | ((d & (BSIZE - 1u)) << 20), __float_as_uint(w[e]));
    }
}

// one block per bucket: LDS-accumulate messages, fused bias+tanh epilogue
__global__ void bucket_step_kernel(const uint2* __restrict__ e8,
                                   const u32* __restrict__ gbase,
                                   const float* __restrict__ v_in,
                                   float* __restrict__ v_out,
                                   const float* __restrict__ bias,
                                   float* __restrict__ out,   // null except last step
                                   int N, int IN, int OUT) {
    __shared__ float acc[BSIZE];
    for (int i = threadIdx.x; i < BSIZE; i += THREADS) acc[i] = 0.0f;
    __syncthreads();
    int b = blockIdx.x;
    u32 beg = gbase[b], end = gbase[b + 1];
    for (u32 e = beg + threadIdx.x; e < end; e += THREADS) {
        uint2 p = e8[e];
        u32 s = p.x & 0xFFFFFu;
        u32 dl = (p.x >> 20) & (BSIZE - 1u);
        atomicAdd(&acc[dl], v_in[s] * __uint_as_float(p.y));
    }
    __syncthreads();
    int base = b << BSHIFT;
    for (int j = threadIdx.x; j < BSIZE; j += THREADS) {
        int idx = base + j;
        if (idx >= N) break;
        float val = acc[j] + (idx >= IN ? bias[idx - IN] : 0.0f);
        bool isOut = idx >= N - OUT;
        float a = isOut ? val : tanhf(val);
        v_out[idx] = a;
        if (out != nullptr && isOut) out[idx - (N - OUT)] = a;
    }
}

// ---------------- fallback path (round-2 atomic version) ----------------

__global__ void prep_kernel(const float* __restrict__ x, const float* __restrict__ bias,
                            float* __restrict__ v, float* __restrict__ nxt,
                            int N, int IN) {
    int i = blockIdx.x * THREADS + threadIdx.x;
    if (i >= N) return;
    v[i]   = (i < IN) ? x[i] : 0.0f;
    nxt[i] = (i < IN) ? 0.0f : bias[i - IN];
}

__global__ void edge_kernel(const int* __restrict__ src, const int* __restrict__ dst,
                            const float* __restrict__ w, const float* __restrict__ v,
                            float* __restrict__ nxt, int E) {
    int k = blockIdx.x * THREADS + threadIdx.x;
    int E4 = E >> 2;
    if (k < E4) {
        int4 s = ((const int4*)src)[k];
        int4 d = ((const int4*)dst)[k];
        float4 wv = ((const float4*)w)[k];
        atomicAdd(&nxt[d.x], v[s.x] * wv.x);
        atomicAdd(&nxt[d.y], v[s.y] * wv.y);
        atomicAdd(&nxt[d.z], v[s.z] * wv.z);
        atomicAdd(&nxt[d.w], v[s.w] * wv.w);
    }
    if (k == 0) {
        for (int e = E4 << 2; e < E; ++e)
            atomicAdd(&nxt[dst[e]], v[src[e]] * w[e]);
    }
}

__global__ void finalize_kernel(float* __restrict__ nxt, float* __restrict__ v,
                                const float* __restrict__ bias, float* __restrict__ out,
                                int N, int IN, int OUT) {
    int i = blockIdx.x * THREADS + threadIdx.x;
    if (i >= N) return;
    float val = nxt[i];
    bool isOut = (i >= N - OUT);
    float a = isOut ? val : tanhf(val);
    v[i] = a;
    nxt[i] = (i < IN) ? 0.0f : bias[i - IN];
    if (out != nullptr && isOut) out[i - (N - OUT)] = a;
}

// ---------------- launch ----------------

extern "C" void kernel_launch(void* const* d_in, const int* in_sizes, int n_in,
                              void* d_out, int out_size, void* d_ws, size_t ws_size,
                              hipStream_t stream) {
    const float* x    = (const float*)d_in[0];
    const float* w    = (const float*)d_in[1];
    const float* bias = (const float*)d_in[2];
    const int* src = (const int*)d_in[3];
    const int* dst = (const int*)d_in[4];

    const int IN  = in_sizes[0];
    const int E   = in_sizes[1];
    const int N   = IN + in_sizes[2];
    const int OUT = out_size;
    const int STEPS = 3;

    // workspace layout for fast path
    uint2* e8     = (uint2*)d_ws;                 // E * 8B
    u32*   ghisto = (u32*)(e8 + E);               // 1024
    u32*   gbase  = ghisto + BSIZE;               // 1025
    u32*   gcursor= gbase + BSIZE + 1;            // 1024
    float* vA     = (float*)(gcursor + BSIZE);    // N
    float* vB     = vA + N;                       // N
    size_t need   = (size_t)((char*)(vB + N) - (char*)d_ws);

    int nBlocks = (N + THREADS - 1) / THREADS;

    if (ws_size >= need && N <= (1 << 20)) {
        int NB = (N + BSIZE - 1) >> BSHIFT;
        hipMemsetAsync(ghisto, 0, BSIZE * sizeof(u32), stream);
        prep2_kernel<<<nBlocks, THREADS, 0, stream>>>(x, vA, N, IN);
        histo_kernel<<<512, THREADS, 0, stream>>>(dst, ghisto, E);
        scan_kernel<<<1, 1024, 0, stream>>>(ghisto, gbase, gcursor, NB);
        scatter_kernel<<<(E + SC_CHUNK - 1) / SC_CHUNK, THREADS, 0, stream>>>(
            src, dst, w, gcursor, e8, E);
        float* vin = vA; float* vout = vB;
        for (int step = 0; step < STEPS; ++step) {
            float* outp = (step == STEPS - 1) ? (float*)d_out : nullptr;
            bucket_step_kernel<<<NB, THREADS, 0, stream>>>(
                e8, gbase, vin, vout, bias, outp, N, IN, OUT);
            float* t = vin; vin = vout; vout = t;
        }
    } else {
        // fallback: round-2 atomic implementation
        float* v   = (float*)d_ws;
        float* nxt = v + N;
        int eBlocks = ((E >> 2) + THREADS - 1) / THREADS;
        prep_kernel<<<nBlocks, THREADS, 0, stream>>>(x, bias, v, nxt, N, IN);
        for (int step = 0; step < STEPS; ++step) {
            edge_kernel<<<eBlocks, THREADS, 0, stream>>>(src, dst, w, v, nxt, E);
            float* outp = (step == STEPS - 1) ? (float*)d_out : nullptr;
            finalize_kernel<<<nBlocks, THREADS, 0, stream>>>(nxt, v, bias, outp, N, IN, OUT);
        }
    }
}

// Round 4
// 962.547 us; speedup vs baseline: 2.2261x; 1.1504x over previous
//
#include <hip/hip_runtime.h>

#define THREADS 256
#define BTHREADS 1024         // bucket_step block size
#define BSHIFT 12
#define BSIZE 4096            // neurons per bucket (16KB LDS fp32 accumulator)
#define NBMAX 256             // max buckets (N <= 2^20 -> <= 256)
#define SC_CHUNK 65536        // edges per scatter block
typedef unsigned int u32;

// ---------------- fast path: bucketized gather ----------------

// v[i] = x[i] for inputs else 0 ; nxt[i] = bias-init (step-0 accumulator)
__global__ void prep_kernel(const float* __restrict__ x, const float* __restrict__ bias,
                            float* __restrict__ v, float* __restrict__ nxt,
                            int N, int IN) {
    int i = blockIdx.x * THREADS + threadIdx.x;
    if (i >= N) return;
    v[i]   = (i < IN) ? x[i] : 0.0f;
    nxt[i] = (i < IN) ? 0.0f : bias[i - IN];
}

// Step-0: v nonzero only for neurons [0,IN) -> ~0.4% of edges active.
__global__ void edge0_kernel(const int* __restrict__ src, const int* __restrict__ dst,
                             const float* __restrict__ w, const float* __restrict__ v,
                             float* __restrict__ nxt, int E, int IN) {
    int k = blockIdx.x * THREADS + threadIdx.x;
    int E4 = E >> 2;
    if (k < E4) {
        int4 s = ((const int4*)src)[k];
        int b = k << 2;
        if (s.x < IN) atomicAdd(&nxt[dst[b + 0]], v[s.x] * w[b + 0]);
        if (s.y < IN) atomicAdd(&nxt[dst[b + 1]], v[s.y] * w[b + 1]);
        if (s.z < IN) atomicAdd(&nxt[dst[b + 2]], v[s.z] * w[b + 2]);
        if (s.w < IN) atomicAdd(&nxt[dst[b + 3]], v[s.w] * w[b + 3]);
    }
    if (k == 0) {
        for (int e = E4 << 2; e < E; ++e) {
            int s = src[e];
            if (s < IN) atomicAdd(&nxt[dst[e]], v[s] * w[e]);
        }
    }
}

// in-place: v = isOutput ? v : tanh(v)
__global__ void finalize0_kernel(float* __restrict__ v, int N, int OUT) {
    int i = blockIdx.x * THREADS + threadIdx.x;
    if (i >= N) return;
    float val = v[i];
    v[i] = (i >= N - OUT) ? val : tanhf(val);
}

// LDS-privatized histogram of dst into coarse buckets
__global__ void histo_kernel(const int* __restrict__ dst, u32* __restrict__ ghisto,
                             int E) {
    __shared__ u32 h[NBMAX];
    for (int i = threadIdx.x; i < NBMAX; i += THREADS) h[i] = 0;
    __syncthreads();
    int stride = gridDim.x * THREADS;
    for (int e = blockIdx.x * THREADS + threadIdx.x; e < E; e += stride)
        atomicAdd(&h[((u32)dst[e]) >> BSHIFT], 1u);
    __syncthreads();
    for (int i = threadIdx.x; i < NBMAX; i += THREADS) {
        u32 c = h[i];
        if (c) atomicAdd(&ghisto[i], c);
    }
}

// single-block exclusive scan over <=NBMAX bucket counts
__global__ void scan_kernel(const u32* __restrict__ ghisto, u32* __restrict__ gbase,
                            u32* __restrict__ gcursor, int NB) {
    __shared__ u32 s[NBMAX];
    int t = threadIdx.x;
    u32 own = (t < NB) ? ghisto[t] : 0u;
    s[t] = own;
    __syncthreads();
    for (int off = 1; off < NBMAX; off <<= 1) {
        u32 v = (t >= off) ? s[t - off] : 0u;
        __syncthreads();
        s[t] += v;
        __syncthreads();
    }
    u32 excl = s[t] - own;
    if (t < NB) { gbase[t] = excl; gcursor[t] = excl; }
    if (t == NB - 1) gbase[NB] = s[t];   // total == E
}

// scatter edges into bucket-grouped records: (src | dst_local<<20, w)
__global__ void scatter_kernel(const int* __restrict__ src, const int* __restrict__ dst,
                               const float* __restrict__ w, u32* __restrict__ gcursor,
                               uint2* __restrict__ e8, int E) {
    __shared__ u32 h[NBMAX];
    int start = blockIdx.x * SC_CHUNK;
    int end = start + SC_CHUNK; if (end > E) end = E;
    for (int i = threadIdx.x; i < NBMAX; i += THREADS) h[i] = 0;
    __syncthreads();
    for (int e = start + threadIdx.x; e < end; e += THREADS)
        atomicAdd(&h[((u32)dst[e]) >> BSHIFT], 1u);
    __syncthreads();
    for (int i = threadIdx.x; i < NBMAX; i += THREADS) {
        u32 c = h[i];
        h[i] = c ? atomicAdd(&gcursor[i], c) : 0u;   // reserve contiguous range
    }
    __syncthreads();
    for (int e = start + threadIdx.x; e < end; e += THREADS) {
        u32 d = (u32)dst[e];
        u32 b0 = d >> BSHIFT;
        u32 pos = atomicAdd(&h[b0], 1u);
        e8[pos] = make_uint2((u32)src[e] | ((d & (BSIZE - 1u)) << 20), __float_as_uint(w[e]));
    }
}

// one block per bucket: LDS-accumulate messages, fused bias+tanh epilogue
__global__ void bucket_step_kernel(const uint2* __restrict__ e8,
                                   const u32* __restrict__ gbase,
                                   const float* __restrict__ v_in,
                                   float* __restrict__ v_out,
                                   const float* __restrict__ bias,
                                   float* __restrict__ out,   // null except last step
                                   int N, int IN, int OUT) {
    __shared__ float acc[BSIZE];
    for (int i = threadIdx.x; i < BSIZE; i += BTHREADS) acc[i] = 0.0f;
    __syncthreads();
    int b = blockIdx.x;
    u32 beg = gbase[b], end = gbase[b + 1];
    for (u32 e = beg + threadIdx.x; e < end; e += BTHREADS) {
        uint2 p = e8[e];
        u32 s = p.x & 0xFFFFFu;
        u32 dl = p.x >> 20;
        atomicAdd(&acc[dl], v_in[s] * __uint_as_float(p.y));
    }
    __syncthreads();
    int base = b << BSHIFT;
    for (int j = threadIdx.x; j < BSIZE; j += BTHREADS) {
        int idx = base + j;
        if (idx >= N) break;
        float val = acc[j] + (idx >= IN ? bias[idx - IN] : 0.0f);
        bool isOut = idx >= N - OUT;
        float a = isOut ? val : tanhf(val);
        v_out[idx] = a;
        if (out != nullptr && isOut) out[idx - (N - OUT)] = a;
    }
}

// ---------------- fallback path (round-2 atomic version) ----------------

__global__ void edge_kernel(const int* __restrict__ src, const int* __restrict__ dst,
                            const float* __restrict__ w, const float* __restrict__ v,
                            float* __restrict__ nxt, int E) {
    int k = blockIdx.x * THREADS + threadIdx.x;
    int E4 = E >> 2;
    if (k < E4) {
        int4 s = ((const int4*)src)[k];
        int4 d = ((const int4*)dst)[k];
        float4 wv = ((const float4*)w)[k];
        atomicAdd(&nxt[d.x], v[s.x] * wv.x);
        atomicAdd(&nxt[d.y], v[s.y] * wv.y);
        atomicAdd(&nxt[d.z], v[s.z] * wv.z);
        atomicAdd(&nxt[d.w], v[s.w] * wv.w);
    }
    if (k == 0) {
        for (int e = E4 << 2; e < E; ++e)
            atomicAdd(&nxt[dst[e]], v[src[e]] * w[e]);
    }
}

__global__ void finalize_kernel(float* __restrict__ nxt, float* __restrict__ v,
                                const float* __restrict__ bias, float* __restrict__ out,
                                int N, int IN, int OUT) {
    int i = blockIdx.x * THREADS + threadIdx.x;
    if (i >= N) return;
    float val = nxt[i];
    bool isOut = (i >= N - OUT);
    float a = isOut ? val : tanhf(val);
    v[i] = a;
    nxt[i] = (i < IN) ? 0.0f : bias[i - IN];
    if (out != nullptr && isOut) out[i - (N - OUT)] = a;
}

// ---------------- launch ----------------

extern "C" void kernel_launch(void* const* d_in, const int* in_sizes, int n_in,
                              void* d_out, int out_size, void* d_ws, size_t ws_size,
                              hipStream_t stream) {
    const float* x    = (const float*)d_in[0];
    const float* w    = (const float*)d_in[1];
    const float* bias = (const float*)d_in[2];
    const int* src = (const int*)d_in[3];
    const int* dst = (const int*)d_in[4];

    const int IN  = in_sizes[0];
    const int E   = in_sizes[1];
    const int N   = IN + in_sizes[2];
    const int OUT = out_size;

    // workspace layout for fast path
    uint2* e8     = (uint2*)d_ws;                 // E * 8B
    u32*   ghisto = (u32*)(e8 + E);               // NBMAX
    u32*   gbase  = ghisto + NBMAX;               // NBMAX+1
    u32*   gcursor= gbase + NBMAX + 1;            // NBMAX
    float* vA     = (float*)(gcursor + NBMAX);    // N
    float* vB     = vA + N;                       // N
    size_t need   = (size_t)((char*)(vB + N) - (char*)d_ws);

    int nBlocks = (N + THREADS - 1) / THREADS;
    int eBlocks = ((E >> 2) + THREADS - 1) / THREADS;

    if (ws_size >= need && N <= (1 << 20)) {
        int NB = (N + BSIZE - 1) >> BSHIFT;
        hipMemsetAsync(ghisto, 0, NBMAX * sizeof(u32), stream);
        // vA = input state; vB = step-0 accumulator (bias-init)
        prep_kernel<<<nBlocks, THREADS, 0, stream>>>(x, bias, vA, vB, N, IN);
        // build bucket-grouped edge records (used by steps 1,2)
        histo_kernel<<<512, THREADS, 0, stream>>>(dst, ghisto, E);
        scan_kernel<<<1, NBMAX, 0, stream>>>(ghisto, gbase, gcursor, NB);
        scatter_kernel<<<(E + SC_CHUNK - 1) / SC_CHUNK, THREADS, 0, stream>>>(
            src, dst, w, gcursor, e8, E);
        // step 0: sparse (only src<IN active)
        edge0_kernel<<<eBlocks, THREADS, 0, stream>>>(src, dst, w, vA, vB, E, IN);
        finalize0_kernel<<<nBlocks, THREADS, 0, stream>>>(vB, N, OUT);
        // steps 1,2: bucketized gather
        bucket_step_kernel<<<NB, BTHREADS, 0, stream>>>(
            e8, gbase, vB, vA, bias, nullptr, N, IN, OUT);
        bucket_step_kernel<<<NB, BTHREADS, 0, stream>>>(
            e8, gbase, vA, vB, bias, (float*)d_out, N, IN, OUT);
    } else {
        // fallback: round-2 atomic implementation
        float* v   = (float*)d_ws;
        float* nxt = v + N;
        prep_kernel<<<nBlocks, THREADS, 0, stream>>>(x, bias, v, nxt, N, IN);
        for (int step = 0; step < 3; ++step) {
            edge_kernel<<<eBlocks, THREADS, 0, stream>>>(src, dst, w, v, nxt, E);
            float* outp = (step == 2) ? (float*)d_out : nullptr;
            finalize_kernel<<<nBlocks, THREADS, 0, stream>>>(nxt, v, bias, outp, N, IN, OUT);
        }
    }
}

// Round 5
// 867.028 us; speedup vs baseline: 2.4714x; 1.1102x over previous
//
#include <hip/hip_runtime.h>

#define THREADS 256
#define BTHREADS 1024         // bucket_step block size
#define SCTHREADS 1024        // scatter block size (occupancy: 16 waves/CU at 306 blocks)
#define BSHIFT 12
#define BSIZE 4096            // neurons per bucket (16KB LDS fp32 accumulator)
#define NBMAX 256             // max buckets (N <= 2^20 -> <= 256)
#define SC_CHUNK 65536        // edges per scatter block
typedef unsigned int u32;

// ---------------- fast path: bucketized gather ----------------

// v[i] = x[i] for inputs else 0 ; nxt[i] = bias-init (step-0 accumulator)
__global__ void prep_kernel(const float* __restrict__ x, const float* __restrict__ bias,
                            float* __restrict__ v, float* __restrict__ nxt,
                            int N, int IN) {
    int i = blockIdx.x * THREADS + threadIdx.x;
    if (i >= N) return;
    v[i]   = (i < IN) ? x[i] : 0.0f;
    nxt[i] = (i < IN) ? 0.0f : bias[i - IN];
}

// Step-0: v nonzero only for neurons [0,IN) -> ~0.4% of edges active.
__global__ void edge0_kernel(const int* __restrict__ src, const int* __restrict__ dst,
                             const float* __restrict__ w, const float* __restrict__ v,
                             float* __restrict__ nxt, int E, int IN) {
    int k = blockIdx.x * THREADS + threadIdx.x;
    int E4 = E >> 2;
    if (k < E4) {
        int4 s = ((const int4*)src)[k];
        int b = k << 2;
        if (s.x < IN) atomicAdd(&nxt[dst[b + 0]], v[s.x] * w[b + 0]);
        if (s.y < IN) atomicAdd(&nxt[dst[b + 1]], v[s.y] * w[b + 1]);
        if (s.z < IN) atomicAdd(&nxt[dst[b + 2]], v[s.z] * w[b + 2]);
        if (s.w < IN) atomicAdd(&nxt[dst[b + 3]], v[s.w] * w[b + 3]);
    }
    if (k == 0) {
        for (int e = E4 << 2; e < E; ++e) {
            int s = src[e];
            if (s < IN) atomicAdd(&nxt[dst[e]], v[s] * w[e]);
        }
    }
}

// in-place: v = isOutput ? v : tanh(v)
__global__ void finalize0_kernel(float* __restrict__ v, int N, int OUT) {
    int i = blockIdx.x * THREADS + threadIdx.x;
    if (i >= N) return;
    float val = v[i];
    v[i] = (i >= N - OUT) ? val : tanhf(val);
}

// LDS-privatized histogram of dst into coarse buckets
__global__ void histo_kernel(const int* __restrict__ dst, u32* __restrict__ ghisto,
                             int E) {
    __shared__ u32 h[NBMAX];
    for (int i = threadIdx.x; i < NBMAX; i += THREADS) h[i] = 0;
    __syncthreads();
    int stride = gridDim.x * THREADS;
    for (int e = blockIdx.x * THREADS + threadIdx.x; e < E; e += stride)
        atomicAdd(&h[((u32)dst[e]) >> BSHIFT], 1u);
    __syncthreads();
    for (int i = threadIdx.x; i < NBMAX; i += THREADS) {
        u32 c = h[i];
        if (c) atomicAdd(&ghisto[i], c);
    }
}

// single-block exclusive scan over <=NBMAX bucket counts
__global__ void scan_kernel(const u32* __restrict__ ghisto, u32* __restrict__ gbase,
                            u32* __restrict__ gcursor, int NB) {
    __shared__ u32 s[NBMAX];
    int t = threadIdx.x;
    u32 own = (t < NB) ? ghisto[t] : 0u;
    s[t] = own;
    __syncthreads();
    for (int off = 1; off < NBMAX; off <<= 1) {
        u32 v = (t >= off) ? s[t - off] : 0u;
        __syncthreads();
        s[t] += v;
        __syncthreads();
    }
    u32 excl = s[t] - own;
    if (t < NB) { gbase[t] = excl; gcursor[t] = excl; }
    if (t == NB - 1) gbase[NB] = s[t];   // total == E
}

// scatter edges into bucket-grouped records: (src | dst_local<<20, w)
__global__ void __launch_bounds__(SCTHREADS)
scatter_kernel(const int* __restrict__ src, const int* __restrict__ dst,
               const float* __restrict__ w, u32* __restrict__ gcursor,
               uint2* __restrict__ e8, int E) {
    __shared__ u32 h[NBMAX];
    int start = blockIdx.x * SC_CHUNK;
    int end = start + SC_CHUNK; if (end > E) end = E;
    for (int i = threadIdx.x; i < NBMAX; i += SCTHREADS) h[i] = 0;
    __syncthreads();
    for (int e = start + threadIdx.x; e < end; e += SCTHREADS)
        atomicAdd(&h[((u32)dst[e]) >> BSHIFT], 1u);
    __syncthreads();
    for (int i = threadIdx.x; i < NBMAX; i += SCTHREADS) {
        u32 c = h[i];
        h[i] = c ? atomicAdd(&gcursor[i], c) : 0u;   // reserve contiguous range
    }
    __syncthreads();
    for (int e = start + threadIdx.x; e < end; e += SCTHREADS) {
        u32 d = (u32)dst[e];
        u32 b0 = d >> BSHIFT;
        u32 pos = atomicAdd(&h[b0], 1u);
        e8[pos] = make_uint2((u32)src[e] | ((d & (BSIZE - 1u)) << 20), __float_as_uint(w[e]));
    }
}

// one block per bucket: LDS-accumulate messages, fused bias+tanh epilogue
__global__ void __launch_bounds__(BTHREADS)
bucket_step_kernel(const uint2* __restrict__ e8,
                   const u32* __restrict__ gbase,
                   const float* __restrict__ v_in,
                   float* __restrict__ v_out,
                   const float* __restrict__ bias,
                   float* __restrict__ out,   // null except last step
                   int N, int IN, int OUT) {
    __shared__ float acc[BSIZE];
    for (int i = threadIdx.x; i < BSIZE; i += BTHREADS) acc[i] = 0.0f;
    __syncthreads();
    int b = blockIdx.x;
    u32 beg = gbase[b], end = gbase[b + 1];
    for (u32 e = beg + threadIdx.x; e < end; e += BTHREADS) {
        uint2 p = e8[e];
        u32 s = p.x & 0xFFFFFu;
        u32 dl = p.x >> 20;
        atomicAdd(&acc[dl], v_in[s] * __uint_as_float(p.y));
    }
    __syncthreads();
    int base = b << BSHIFT;
    for (int j = threadIdx.x; j < BSIZE; j += BTHREADS) {
        int idx = base + j;
        if (idx >= N) break;
        float val = acc[j] + (idx >= IN ? bias[idx - IN] : 0.0f);
        bool isOut = idx >= N - OUT;
        float a = isOut ? val : tanhf(val);
        v_out[idx] = a;
        if (out != nullptr && isOut) out[idx - (N - OUT)] = a;
    }
}

// ---------------- fallback path (round-2 atomic version) ----------------

__global__ void edge_kernel(const int* __restrict__ src, const int* __restrict__ dst,
                            const float* __restrict__ w, const float* __restrict__ v,
                            float* __restrict__ nxt, int E) {
    int k = blockIdx.x * THREADS + threadIdx.x;
    int E4 = E >> 2;
    if (k < E4) {
        int4 s = ((const int4*)src)[k];
        int4 d = ((const int4*)dst)[k];
        float4 wv = ((const float4*)w)[k];
        atomicAdd(&nxt[d.x], v[s.x] * wv.x);
        atomicAdd(&nxt[d.y], v[s.y] * wv.y);
        atomicAdd(&nxt[d.z], v[s.z] * wv.z);
        atomicAdd(&nxt[d.w], v[s.w] * wv.w);
    }
    if (k == 0) {
        for (int e = E4 << 2; e < E; ++e)
            atomicAdd(&nxt[dst[e]], v[src[e]] * w[e]);
    }
}

__global__ void finalize_kernel(float* __restrict__ nxt, float* __restrict__ v,
                                const float* __restrict__ bias, float* __restrict__ out,
                                int N, int IN, int OUT) {
    int i = blockIdx.x * THREADS + threadIdx.x;
    if (i >= N) return;
    float val = nxt[i];
    bool isOut = (i >= N - OUT);
    float a = isOut ? val : tanhf(val);
    v[i] = a;
    nxt[i] = (i < IN) ? 0.0f : bias[i - IN];
    if (out != nullptr && isOut) out[i - (N - OUT)] = a;
}

// ---------------- launch ----------------

extern "C" void kernel_launch(void* const* d_in, const int* in_sizes, int n_in,
                              void* d_out, int out_size, void* d_ws, size_t ws_size,
                              hipStream_t stream) {
    const float* x    = (const float*)d_in[0];
    const float* w    = (const float*)d_in[1];
    const float* bias = (const float*)d_in[2];
    const int* src = (const int*)d_in[3];
    const int* dst = (const int*)d_in[4];

    const int IN  = in_sizes[0];
    const int E   = in_sizes[1];
    const int N   = IN + in_sizes[2];
    const int OUT = out_size;

    // workspace layout for fast path
    uint2* e8     = (uint2*)d_ws;                 // E * 8B
    u32*   ghisto = (u32*)(e8 + E);               // NBMAX
    u32*   gbase  = ghisto + NBMAX;               // NBMAX+1
    u32*   gcursor= gbase + NBMAX + 1;            // NBMAX
    float* vA     = (float*)(gcursor + NBMAX);    // N
    float* vB     = vA + N;                       // N
    size_t need   = (size_t)((char*)(vB + N) - (char*)d_ws);

    int nBlocks = (N + THREADS - 1) / THREADS;
    int eBlocks = ((E >> 2) + THREADS - 1) / THREADS;

    if (ws_size >= need && N <= (1 << 20)) {
        int NB = (N + BSIZE - 1) >> BSHIFT;
        hipMemsetAsync(ghisto, 0, NBMAX * sizeof(u32), stream);
        // vA = input state; vB = step-0 accumulator (bias-init)
        prep_kernel<<<nBlocks, THREADS, 0, stream>>>(x, bias, vA, vB, N, IN);
        // build bucket-grouped edge records (used by steps 1,2)
        histo_kernel<<<1024, THREADS, 0, stream>>>(dst, ghisto, E);
        scan_kernel<<<1, NBMAX, 0, stream>>>(ghisto, gbase, gcursor, NB);
        scatter_kernel<<<(E + SC_CHUNK - 1) / SC_CHUNK, SCTHREADS, 0, stream>>>(
            src, dst, w, gcursor, e8, E);
        // step 0: sparse (only src<IN active)
        edge0_kernel<<<eBlocks, THREADS, 0, stream>>>(src, dst, w, vA, vB, E, IN);
        finalize0_kernel<<<nBlocks, THREADS, 0, stream>>>(vB, N, OUT);
        // steps 1,2: bucketized gather
        bucket_step_kernel<<<NB, BTHREADS, 0, stream>>>(
            e8, gbase, vB, vA, bias, nullptr, N, IN, OUT);
        bucket_step_kernel<<<NB, BTHREADS, 0, stream>>>(
            e8, gbase, vA, vB, bias, (float*)d_out, N, IN, OUT);
    } else {
        // fallback: round-2 atomic implementation
        float* v   = (float*)d_ws;
        float* nxt = v + N;
        prep_kernel<<<nBlocks, THREADS, 0, stream>>>(x, bias, v, nxt, N, IN);
        for (int step = 0; step < 3; ++step) {
            edge_kernel<<<eBlocks, THREADS, 0, stream>>>(src, dst, w, v, nxt, E);
            float* outp = (step == 2) ? (float*)d_out : nullptr;
            finalize_kernel<<<nBlocks, THREADS, 0, stream>>>(nxt, v, bias, outp, N, IN, OUT);
        }
    }
}

// Round 6
// 708.764 us; speedup vs baseline: 3.0232x; 1.2233x over previous
//
#include <hip/hip_runtime.h>

#define THREADS 256
#define BTHREADS 1024         // bucket_step block size
#define SCTHREADS 1024        // scatter block size
#define BSHIFT 12
#define BSIZE 4096            // neurons per bucket (16KB LDS fp32 accumulator)
#define NBMAX 256             // max buckets (N <= 2^20 -> <= 256)
#define SC_CHUNK 32768        // edges per scatter block (4 passes)
#define PASS_EDGES 8192       // edges staged per pass (64 KB LDS)
#define EPT 8                 // edges per thread per pass
typedef unsigned int u32;
typedef unsigned long long u64;

// ---------------- fast path: bucketized gather ----------------

// v[i] = x[i] for inputs else 0 ; nxt[i] = bias-init (step-0 accumulator)
__global__ void prep_kernel(const float* __restrict__ x, const float* __restrict__ bias,
                            float* __restrict__ v, float* __restrict__ nxt,
                            int N, int IN) {
    int i = blockIdx.x * THREADS + threadIdx.x;
    if (i >= N) return;
    v[i]   = (i < IN) ? x[i] : 0.0f;
    nxt[i] = (i < IN) ? 0.0f : bias[i - IN];
}

// Step-0: v nonzero only for neurons [0,IN) -> ~0.4% of edges active.
__global__ void edge0_kernel(const int* __restrict__ src, const int* __restrict__ dst,
                             const float* __restrict__ w, const float* __restrict__ v,
                             float* __restrict__ nxt, int E, int IN) {
    int k = blockIdx.x * THREADS + threadIdx.x;
    int E4 = E >> 2;
    if (k < E4) {
        int4 s = ((const int4*)src)[k];
        int b = k << 2;
        if (s.x < IN) atomicAdd(&nxt[dst[b + 0]], v[s.x] * w[b + 0]);
        if (s.y < IN) atomicAdd(&nxt[dst[b + 1]], v[s.y] * w[b + 1]);
        if (s.z < IN) atomicAdd(&nxt[dst[b + 2]], v[s.z] * w[b + 2]);
        if (s.w < IN) atomicAdd(&nxt[dst[b + 3]], v[s.w] * w[b + 3]);
    }
    if (k == 0) {
        for (int e = E4 << 2; e < E; ++e) {
            int s = src[e];
            if (s < IN) atomicAdd(&nxt[dst[e]], v[s] * w[e]);
        }
    }
}

// in-place: v = isOutput ? v : tanh(v)
__global__ void finalize0_kernel(float* __restrict__ v, int N, int OUT) {
    int i = blockIdx.x * THREADS + threadIdx.x;
    if (i >= N) return;
    float val = v[i];
    v[i] = (i >= N - OUT) ? val : tanhf(val);
}

// LDS-privatized histogram of dst into coarse buckets
__global__ void histo_kernel(const int* __restrict__ dst, u32* __restrict__ ghisto,
                             int E) {
    __shared__ u32 h[NBMAX];
    for (int i = threadIdx.x; i < NBMAX; i += THREADS) h[i] = 0;
    __syncthreads();
    int stride = gridDim.x * THREADS;
    for (int e = blockIdx.x * THREADS + threadIdx.x; e < E; e += stride)
        atomicAdd(&h[((u32)dst[e]) >> BSHIFT], 1u);
    __syncthreads();
    for (int i = threadIdx.x; i < NBMAX; i += THREADS) {
        u32 c = h[i];
        if (c) atomicAdd(&ghisto[i], c);
    }
}

// single-block exclusive scan over <=NBMAX bucket counts
__global__ void scan_kernel(const u32* __restrict__ ghisto, u32* __restrict__ gbase,
                            u32* __restrict__ gcursor, int NB) {
    __shared__ u32 s[NBMAX];
    int t = threadIdx.x;
    u32 own = (t < NB) ? ghisto[t] : 0u;
    s[t] = own;
    __syncthreads();
    for (int off = 1; off < NBMAX; off <<= 1) {
        u32 v = (t >= off) ? s[t - off] : 0u;
        __syncthreads();
        s[t] += v;
        __syncthreads();
    }
    u32 excl = s[t] - own;
    if (t < NB) { gbase[t] = excl; gcursor[t] = excl; }
    if (t == NB - 1) gbase[NB] = s[t];   // total == E
}

// scatter with in-LDS counting sort per 8K-edge pass -> coalesced run stores
__global__ void __launch_bounds__(SCTHREADS)
scatter_kernel(const int* __restrict__ src, const int* __restrict__ dst,
               const float* __restrict__ w, u32* __restrict__ gcursor,
               uint2* __restrict__ e8, int E) {
    __shared__ uint2 stage[PASS_EDGES];   // 64 KB
    __shared__ u32 hc[NBMAX];             // per-pass histogram, then rank counter
    __shared__ u32 runStart[NBMAX + 1];   // exclusive scan of hc
    __shared__ u32 gpos[NBMAX];           // global write base per bucket this pass
    __shared__ u32 sc[NBMAX];             // scan temp

    const int tid = threadIdx.x;
    int blockStart = blockIdx.x * SC_CHUNK;
    int blockEnd = blockStart + SC_CHUNK; if (blockEnd > E) blockEnd = E;

    for (int ps = blockStart; ps < blockEnd; ps += PASS_EDGES) {
        // ---- load up to EPT edges into registers ----
        int base = ps + tid * EPT;
        u32 pk[EPT]; u32 bk[EPT]; u32 wb[EPT];
        int cnt = 0;
        if (base + EPT <= blockEnd) {
            int4 s0 = *(const int4*)(src + base), s1 = *(const int4*)(src + base + 4);
            int4 d0 = *(const int4*)(dst + base), d1 = *(const int4*)(dst + base + 4);
            float4 w0 = *(const float4*)(w + base), w1 = *(const float4*)(w + base + 4);
            int ss[EPT] = {s0.x, s0.y, s0.z, s0.w, s1.x, s1.y, s1.z, s1.w};
            int dd[EPT] = {d0.x, d0.y, d0.z, d0.w, d1.x, d1.y, d1.z, d1.w};
            float ww[EPT] = {w0.x, w0.y, w0.z, w0.w, w1.x, w1.y, w1.z, w1.w};
            cnt = EPT;
            #pragma unroll
            for (int i = 0; i < EPT; ++i) {
                u32 d = (u32)dd[i];
                bk[i] = d >> BSHIFT;
                pk[i] = (u32)ss[i] | ((d & (BSIZE - 1u)) << 20);
                wb[i] = __float_as_uint(ww[i]);
            }
        } else {
            for (int i = 0; i < EPT; ++i) {
                int e = base + i;
                if (e < blockEnd) {
                    u32 d = (u32)dst[e];
                    bk[cnt] = d >> BSHIFT;
                    pk[cnt] = (u32)src[e] | ((d & (BSIZE - 1u)) << 20);
                    wb[cnt] = __float_as_uint(w[e]);
                    ++cnt;
                }
            }
        }
        // ---- zero + histogram ----
        if (tid < NBMAX) hc[tid] = 0;
        __syncthreads();
        for (int i = 0; i < cnt; ++i) atomicAdd(&hc[bk[i]], 1u);
        __syncthreads();
        // ---- exclusive scan (Hillis-Steele over 256 entries) ----
        u32 own = (tid < NBMAX) ? hc[tid] : 0u;
        if (tid < NBMAX) sc[tid] = own;
        __syncthreads();
        for (int off = 1; off < NBMAX; off <<= 1) {
            u32 t = 0;
            if (tid < NBMAX && tid >= off) t = sc[tid - off];
            __syncthreads();
            if (tid < NBMAX) sc[tid] += t;
            __syncthreads();
        }
        if (tid < NBMAX) {
            runStart[tid] = sc[tid] - own;
            gpos[tid] = own ? atomicAdd(&gcursor[tid], own) : 0u;
            hc[tid] = 0;   // reuse as rank counter
        }
        if (tid == NBMAX - 1) runStart[NBMAX] = sc[tid];
        __syncthreads();
        // ---- ranked placement into LDS (counting sort) ----
        for (int i = 0; i < cnt; ++i) {
            u32 r = atomicAdd(&hc[bk[i]], 1u);
            stage[runStart[bk[i]] + r] = make_uint2(pk[i], wb[i]);
        }
        __syncthreads();
        // ---- coalesced copy-out: one wave per bucket run ----
        int wave = tid >> 6, lane = tid & 63;
        for (int b = wave; b < NBMAX; b += (SCTHREADS >> 6)) {
            u32 s0 = runStart[b], s1 = runStart[b + 1], gp = gpos[b];
            for (u32 j = s0 + lane; j < s1; j += 64)
                e8[gp + (j - s0)] = stage[j];
        }
        __syncthreads();   // protect stage/runStart/gpos before next pass
    }
}

// one block per bucket: LDS-accumulate messages, fused bias+tanh epilogue
__global__ void __launch_bounds__(BTHREADS)
bucket_step_kernel(const uint2* __restrict__ e8,
                   const u32* __restrict__ gbase,
                   const float* __restrict__ v_in,
                   float* __restrict__ v_out,
                   const float* __restrict__ bias,
                   float* __restrict__ out,   // null except last step
                   int N, int IN, int OUT) {
    __shared__ float acc[BSIZE];
    for (int i = threadIdx.x; i < BSIZE; i += BTHREADS) acc[i] = 0.0f;
    __syncthreads();
    int b = blockIdx.x;
    u32 beg = gbase[b], end = gbase[b + 1];
    for (u32 e = beg + threadIdx.x; e < end; e += BTHREADS) {
        // nontemporal: e8 is a single-use 160MB stream; keep v_in in L2
        u64 pv = __builtin_nontemporal_load((const u64*)(e8 + e));
        u32 px = (u32)pv;
        float pw = __uint_as_float((u32)(pv >> 32));
        u32 s = px & 0xFFFFFu;
        u32 dl = px >> 20;
        atomicAdd(&acc[dl], v_in[s] * pw);
    }
    __syncthreads();
    int base = b << BSHIFT;
    for (int j = threadIdx.x; j < BSIZE; j += BTHREADS) {
        int idx = base + j;
        if (idx >= N) break;
        float val = acc[j] + (idx >= IN ? bias[idx - IN] : 0.0f);
        bool isOut = idx >= N - OUT;
        float a = isOut ? val : tanhf(val);
        v_out[idx] = a;
        if (out != nullptr && isOut) out[idx - (N - OUT)] = a;
    }
}

// ---------------- fallback path (round-2 atomic version) ----------------

__global__ void edge_kernel(const int* __restrict__ src, const int* __restrict__ dst,
                            const float* __restrict__ w, const float* __restrict__ v,
                            float* __restrict__ nxt, int E) {
    int k = blockIdx.x * THREADS + threadIdx.x;
    int E4 = E >> 2;
    if (k < E4) {
        int4 s = ((const int4*)src)[k];
        int4 d = ((const int4*)dst)[k];
        float4 wv = ((const float4*)w)[k];
        atomicAdd(&nxt[d.x], v[s.x] * wv.x);
        atomicAdd(&nxt[d.y], v[s.y] * wv.y);
        atomicAdd(&nxt[d.z], v[s.z] * wv.z);
        atomicAdd(&nxt[d.w], v[s.w] * wv.w);
    }
    if (k == 0) {
        for (int e = E4 << 2; e < E; ++e)
            atomicAdd(&nxt[dst[e]], v[src[e]] * w[e]);
    }
}

__global__ void finalize_kernel(float* __restrict__ nxt, float* __restrict__ v,
                                const float* __restrict__ bias, float* __restrict__ out,
                                int N, int IN, int OUT) {
    int i = blockIdx.x * THREADS + threadIdx.x;
    if (i >= N) return;
    float val = nxt[i];
    bool isOut = (i >= N - OUT);
    float a = isOut ? val : tanhf(val);
    v[i] = a;
    nxt[i] = (i < IN) ? 0.0f : bias[i - IN];
    if (out != nullptr && isOut) out[i - (N - OUT)] = a;
}

// ---------------- launch ----------------

extern "C" void kernel_launch(void* const* d_in, const int* in_sizes, int n_in,
                              void* d_out, int out_size, void* d_ws, size_t ws_size,
                              hipStream_t stream) {
    const float* x    = (const float*)d_in[0];
    const float* w    = (const float*)d_in[1];
    const float* bias = (const float*)d_in[2];
    const int* src = (const int*)d_in[3];
    const int* dst = (const int*)d_in[4];

    const int IN  = in_sizes[0];
    const int E   = in_sizes[1];
    const int N   = IN + in_sizes[2];
    const int OUT = out_size;

    // workspace layout for fast path
    uint2* e8     = (uint2*)d_ws;                 // E * 8B
    u32*   ghisto = (u32*)(e8 + E);               // NBMAX
    u32*   gbase  = ghisto + NBMAX;               // NBMAX+1
    u32*   gcursor= gbase + NBMAX + 1;            // NBMAX
    float* vA     = (float*)(gcursor + NBMAX);    // N
    float* vB     = vA + N;                       // N
    size_t need   = (size_t)((char*)(vB + N) - (char*)d_ws);

    int nBlocks = (N + THREADS - 1) / THREADS;
    int eBlocks = ((E >> 2) + THREADS - 1) / THREADS;

    if (ws_size >= need && N <= (1 << 20)) {
        int NB = (N + BSIZE - 1) >> BSHIFT;
        hipMemsetAsync(ghisto, 0, NBMAX * sizeof(u32), stream);
        // vA = input state; vB = step-0 accumulator (bias-init)
        prep_kernel<<<nBlocks, THREADS, 0, stream>>>(x, bias, vA, vB, N, IN);
        // build bucket-grouped edge records (used by steps 1,2)
        histo_kernel<<<1024, THREADS, 0, stream>>>(dst, ghisto, E);
        scan_kernel<<<1, NBMAX, 0, stream>>>(ghisto, gbase, gcursor, NB);
        scatter_kernel<<<(E + SC_CHUNK - 1) / SC_CHUNK, SCTHREADS, 0, stream>>>(
            src, dst, w, gcursor, e8, E);
        // step 0: sparse (only src<IN active)
        edge0_kernel<<<eBlocks, THREADS, 0, stream>>>(src, dst, w, vA, vB, E, IN);
        finalize0_kernel<<<nBlocks, THREADS, 0, stream>>>(vB, N, OUT);
        // steps 1,2: bucketized gather
        bucket_step_kernel<<<NB, BTHREADS, 0, stream>>>(
            e8, gbase, vB, vA, bias, nullptr, N, IN, OUT);
        bucket_step_kernel<<<NB, BTHREADS, 0, stream>>>(
            e8, gbase, vA, vB, bias, (float*)d_out, N, IN, OUT);
    } else {
        // fallback: round-2 atomic implementation
        float* v   = (float*)d_ws;
        float* nxt = v + N;
        prep_kernel<<<nBlocks, THREADS, 0, stream>>>(x, bias, v, nxt, N, IN);
        for (int step = 0; step < 3; ++step) {
            edge_kernel<<<eBlocks, THREADS, 0, stream>>>(src, dst, w, v, nxt, E);
            float* outp = (step == 2) ? (float*)d_out : nullptr;
            finalize_kernel<<<nBlocks, THREADS, 0, stream>>>(nxt, v, bias, outp, N, IN, OUT);
        }
    }
}